// Round 3
// baseline (70333.820 us; speedup 1.0000x reference)
//
#include <hip/hip_runtime.h>
#include <hip/hip_bf16.h>

// LSTM, S=4096, D=1024, H=2048, batch=1.
// Plan:
//  1) gates_gemm: Gin[t][k] = emb[x[t]] . W_ih[k] + b_ih[k] + b_hh[k]  (fp32 tiled GEMM, parallel)
//  2) lstm_seq:   persistent kernel, 128 blocks x 512 threads, W_hh in VGPRs as fp16,
//                 per-step grid sync via agent-scope flags + double-buffered h.

typedef unsigned int uint;
typedef _Float16 half2v __attribute__((ext_vector_type(2)));

#define NB 128   // LSTM blocks (<=256 CUs -> co-residency guaranteed by capacity)
#define NT 512   // threads per LSTM block
#define UPB 16   // hidden units per block (128*16 = 2048)

__device__ __forceinline__ uint packh(float a, float b) {
    half2v h; h.x = (_Float16)a; h.y = (_Float16)b;   // RTN conversions
    return __builtin_bit_cast(uint, h);
}
__device__ __forceinline__ float lo16(uint u) {
    half2v h = __builtin_bit_cast(half2v, u); return (float)h.x;
}
__device__ __forceinline__ float hi16(uint u) {
    half2v h = __builtin_bit_cast(half2v, u); return (float)h.y;
}
__device__ __forceinline__ float sigm(float x) { return 1.f / (1.f + __expf(-x)); }
__device__ __forceinline__ float tanh_fast(float x) {
    float t = fabsf(x);
    float e = __expf(-2.f * t);
    float r = (1.f - e) / (1.f + e);
    return copysignf(r, x);
}

// ---------------------------------------------------------------------------
// Input-gate GEMM: Gin[trow][k] for trow in [0,T) chunk-local, k in [0,8192)
// C = A(64 x 1024, gathered emb rows) . B^T(8192 x 1024 row-major) tiles 64x64, BK=32
// ---------------------------------------------------------------------------
__global__ __launch_bounds__(256, 2) void gates_gemm(
    const int* __restrict__ x, const float* __restrict__ emb,
    const float* __restrict__ Wih, const float* __restrict__ bih,
    const float* __restrict__ bhh, float* __restrict__ Gin, int t0)
{
    __shared__ float As[32][68];   // [kk][t]  (+4 pad: conflict-friendly)
    __shared__ float Bs[32][68];   // [kk][k]
    __shared__ int xb[64];

    const int tid = threadIdx.x;
    const int bt = blockIdx.x, bk = blockIdx.y;
    if (tid < 64) xb[tid] = x[t0 + bt * 64 + tid];
    __syncthreads();

    const int tx = tid & 15, ty = tid >> 4;
    const int lrow = tid >> 2;          // 0..63
    const int lcol = (tid & 3) * 8;     // 0,8,16,24

    const float* arow0 = emb + (size_t)xb[lrow] * 1024 + lcol;
    const float* brow0 = Wih + (size_t)(bk * 64 + lrow) * 1024 + lcol;

    float acc[4][4] = {};

    for (int d0 = 0; d0 < 1024; d0 += 32) {
        float4 a0 = *(const float4*)(arow0 + d0);
        float4 a1 = *(const float4*)(arow0 + d0 + 4);
        float4 b0 = *(const float4*)(brow0 + d0);
        float4 b1 = *(const float4*)(brow0 + d0 + 4);
        __syncthreads();   // previous tile's compute done before overwrite
        As[lcol + 0][lrow] = a0.x; As[lcol + 1][lrow] = a0.y;
        As[lcol + 2][lrow] = a0.z; As[lcol + 3][lrow] = a0.w;
        As[lcol + 4][lrow] = a1.x; As[lcol + 5][lrow] = a1.y;
        As[lcol + 6][lrow] = a1.z; As[lcol + 7][lrow] = a1.w;
        Bs[lcol + 0][lrow] = b0.x; Bs[lcol + 1][lrow] = b0.y;
        Bs[lcol + 2][lrow] = b0.z; Bs[lcol + 3][lrow] = b0.w;
        Bs[lcol + 4][lrow] = b1.x; Bs[lcol + 5][lrow] = b1.y;
        Bs[lcol + 6][lrow] = b1.z; Bs[lcol + 7][lrow] = b1.w;
        __syncthreads();
#pragma unroll
        for (int kk = 0; kk < 32; kk++) {
            float4 av = *(const float4*)&As[kk][ty * 4];
            float4 bv = *(const float4*)&Bs[kk][tx * 4];
#define FMA4(i, aval)                                        \
            acc[i][0] = fmaf(aval, bv.x, acc[i][0]);         \
            acc[i][1] = fmaf(aval, bv.y, acc[i][1]);         \
            acc[i][2] = fmaf(aval, bv.z, acc[i][2]);         \
            acc[i][3] = fmaf(aval, bv.w, acc[i][3]);
            FMA4(0, av.x) FMA4(1, av.y) FMA4(2, av.z) FMA4(3, av.w)
#undef FMA4
        }
    }

    const int kg = bk * 64 + tx * 4;
    float bx = bih[kg + 0] + bhh[kg + 0];
    float by = bih[kg + 1] + bhh[kg + 1];
    float bz = bih[kg + 2] + bhh[kg + 2];
    float bw = bih[kg + 3] + bhh[kg + 3];
#pragma unroll
    for (int i = 0; i < 4; i++) {
        int trow = bt * 64 + ty * 4 + i;   // chunk-local time index
        float4 o;
        o.x = acc[i][0] + bx; o.y = acc[i][1] + by;
        o.z = acc[i][2] + bz; o.w = acc[i][3] + bw;
        *(float4*)&Gin[(size_t)trow * 8192 + kg] = o;
    }
}

// ---------------------------------------------------------------------------
// Persistent sequential LSTM. Block b owns hidden units [b*16, b*16+16).
// thread: r = tid>>3 in [0,64) = row (gate*16+unit), s = tid&7 = K-slice of 256.
// W_hh rows register-resident as fp16 pairs (128 VGPRs), rotated by s so the
// per-step LDS h reads hit 8 distinct banks (broadcast across the 8 r-lanes).
// ---------------------------------------------------------------------------
__global__ __launch_bounds__(NT, 2) void lstm_seq(
    const float* __restrict__ Whh, const float* __restrict__ Gin,
    float* __restrict__ hbuf /*2x2048*/, float* __restrict__ cbuf /*2048*/,
    uint* __restrict__ flags /*NB*/, float* __restrict__ out, int t0, int T)
{
    const int b = blockIdx.x;
    const int tid = threadIdx.x;
    const int r = tid >> 3;       // 0..63
    const int s = tid & 7;        // 0..7
    const int gate = r >> 4;      // 0..3 (i,f,g,o)
    const int ul = r & 15;        // unit local
    const int R = gate * 2048 + b * UPB + ul;   // global row of W_hh / gates

    __shared__ float h4[2048];
    __shared__ float sdot[64];

    // --- load this lane's 256 weights as fp16 pairs, rotated by slice ---
    uint wreg[128];
    const float* wrow = Whh + (size_t)R * 2048 + s * 256;
#pragma unroll
    for (int m = 0; m < 32; m++) {
        int cg = (m + s) & 31;                       // rotation applied at load
        float4 f0 = *(const float4*)(wrow + 8 * cg);
        float4 f1 = *(const float4*)(wrow + 8 * cg + 4);
        wreg[4 * m + 0] = packh(f0.x, f0.y);
        wreg[4 * m + 1] = packh(f0.z, f0.w);
        wreg[4 * m + 2] = packh(f1.x, f1.y);
        wreg[4 * m + 3] = packh(f1.z, f1.w);
    }
    float c_reg = (tid < UPB) ? cbuf[b * UPB + tid] : 0.f;

    for (int t = 0; t < T; ++t) {
        const int tg = t0 + t;
        // ---- wait for all blocks to have published h_{tg-1} ----
        // Only the first NB threads poll (one flag each) to minimize L2
        // atomic-load traffic on the critical sync path.
        const uint target = (uint)tg;
        if (tid < NB) {
            while (__hip_atomic_load(&flags[tid], __ATOMIC_RELAXED,
                                     __HIP_MEMORY_SCOPE_AGENT) < target) {
                __builtin_amdgcn_s_sleep(1);
            }
        }
        __builtin_amdgcn_fence(__ATOMIC_ACQUIRE, "agent");
        __syncthreads();

        // ---- stage h_{tg-1} (fp32) into LDS ----
        const float* hrd = hbuf + (size_t)(tg & 1) * 2048;
        float4 hv = *(const float4*)(hrd + 4 * tid);
        *(float4*)&h4[4 * tid] = hv;
        __syncthreads();

        // ---- prefetch this step's input-gate contributions ----
        float gi = 0.f, gf = 0.f, gg = 0.f, go = 0.f;
        if (tid < UPB) {
            const float* gp = Gin + (size_t)t * 8192 + b * UPB + tid;
            gi = gp[0]; gf = gp[2048]; gg = gp[4096]; go = gp[6144];
        }

        // ---- partial dot: 256 MACs (fp16 w x fp32 h) ----
        float acc = 0.f;
        const float* hbase = &h4[s * 256];
#pragma unroll
        for (int j = 0; j < 32; j++) {
            int cc = (j + s) & 31;
            const float4* hp = (const float4*)(hbase + 8 * cc);
            float4 h0 = hp[0];
            float4 h1 = hp[1];
            uint w0 = wreg[4 * j + 0], w1 = wreg[4 * j + 1];
            uint w2 = wreg[4 * j + 2], w3 = wreg[4 * j + 3];
            acc = fmaf(lo16(w0), h0.x, acc);
            acc = fmaf(hi16(w0), h0.y, acc);
            acc = fmaf(lo16(w1), h0.z, acc);
            acc = fmaf(hi16(w1), h0.w, acc);
            acc = fmaf(lo16(w2), h1.x, acc);
            acc = fmaf(hi16(w2), h1.y, acc);
            acc = fmaf(lo16(w3), h1.z, acc);
            acc = fmaf(hi16(w3), h1.w, acc);
        }
        acc += __shfl_xor(acc, 1, 64);
        acc += __shfl_xor(acc, 2, 64);
        acc += __shfl_xor(acc, 4, 64);
        if (s == 0) sdot[r] = acc;
        __syncthreads();

        // ---- gate math + state update (16 threads) ----
        if (tid < UPB) {
            float zi = sdot[tid]      + gi;
            float zf = sdot[16 + tid] + gf;
            float zg = sdot[32 + tid] + gg;
            float zo = sdot[48 + tid] + go;
            float si = sigm(zi), sf = sigm(zf), so = sigm(zo);
            float tg_ = tanh_fast(zg);
            c_reg = sf * c_reg + si * tg_;
            float h = so * tanh_fast(c_reg);
            __hip_atomic_store(&hbuf[(size_t)((tg + 1) & 1) * 2048 + b * UPB + tid],
                               h, __ATOMIC_RELAXED, __HIP_MEMORY_SCOPE_AGENT);
            out[(size_t)tg * 2048 + b * UPB + tid] = h;
        }
        __syncthreads();   // drains vmcnt -> h stores globally visible
        if (tid == 0) {
            __hip_atomic_store(&flags[b], (uint)(tg + 1), __ATOMIC_RELEASE,
                               __HIP_MEMORY_SCOPE_AGENT);
        }
    }
    if (tid < UPB) cbuf[b * UPB + tid] = c_reg;   // persist c across chunk launches
}

// ---------------------------------------------------------------------------
__global__ void init_state(const float* __restrict__ h0, const float* __restrict__ c0,
                           float* __restrict__ hbuf, float* __restrict__ cbuf,
                           uint* __restrict__ flags)
{
    int t = blockIdx.x * 256 + threadIdx.x;
    if (t < 2048) { hbuf[t] = h0[t]; cbuf[t] = c0[t]; }
    if (t < NB) flags[t] = 0u;
}

extern "C" void kernel_launch(void* const* d_in, const int* in_sizes, int n_in,
                              void* d_out, int out_size, void* d_ws, size_t ws_size,
                              hipStream_t stream)
{
    const int*   x    = (const int*)d_in[0];
    const float* emb  = (const float*)d_in[1];
    const float* Wih  = (const float*)d_in[2];
    const float* Whh  = (const float*)d_in[3];
    const float* bih  = (const float*)d_in[4];
    const float* bhh  = (const float*)d_in[5];
    const float* h0   = (const float*)d_in[6];
    const float* c0   = (const float*)d_in[7];
    float* out = (float*)d_out;

    // workspace layout: [flags 512B pad 4K][hbuf 16K][cbuf 8K pad to 32K][Gin T*32K]
    uint*  flags = (uint*)d_ws;
    float* hbuf  = (float*)((char*)d_ws + 4096);
    float* cbuf  = (float*)((char*)d_ws + 4096 + 16384);
    float* Gin   = (float*)((char*)d_ws + 32768);

    int T = 128;
    const int cands[5] = {4096, 2048, 1024, 512, 256};
    for (int i = 0; i < 5; i++) {
        if (32768 + (size_t)cands[i] * 8192 * 4 <= ws_size) { T = cands[i]; break; }
    }

    init_state<<<8, 256, 0, stream>>>(h0, c0, hbuf, cbuf, flags);
    const int nC = 4096 / T;
    for (int c = 0; c < nC; ++c) {
        const int t0 = c * T;
        gates_gemm<<<dim3(T / 64, 128), 256, 0, stream>>>(x, emb, Wih, bih, bhh, Gin, t0);
        lstm_seq<<<NB, NT, 0, stream>>>(Whh, Gin, hbuf, cbuf, flags, out, t0, T);
    }
}

// Round 4
// 25379.213 us; speedup vs baseline: 2.7713x; 2.7713x over previous
//
#include <hip/hip_runtime.h>
#include <hip/hip_bf16.h>

// LSTM, S=4096, D=1024, H=2048, batch=1.
//  1) gates_gemm: Gin[t][k] = emb[x[t]] . W_ih[k] + b_ih[k] + b_hh[k]  (fp32 tiled GEMM)
//  2) lstm_seq: persistent, 256 blocks x 512 thr (1 block/CU), W_hh in 64 VGPRs as
//     packed fp16, h carried as packed fp16, v_dot2 MACs. Cross-block sync via
//     RELAXED agent-scope atomics only (LLC-coherent) + vmcnt drain — NO
//     release/acquire fences (those emit buffer_wbl2/buffer_inv cache walks,
//     which cost ~16us/step in round 3).

typedef unsigned int uint;
typedef _Float16 half2v __attribute__((ext_vector_type(2)));

#define NB 256   // LSTM blocks = 1 per CU
#define NT 512   // threads per LSTM block
#define UPB 8    // hidden units per block (256*8 = 2048)

__device__ __forceinline__ uint packh(float a, float b) {
    half2v h; h.x = (_Float16)a; h.y = (_Float16)b;   // RTN conversions
    return __builtin_bit_cast(uint, h);
}
__device__ __forceinline__ float dot2acc(uint w, uint h, float acc) {
#if __has_builtin(__builtin_amdgcn_fdot2)
    return __builtin_amdgcn_fdot2(__builtin_bit_cast(half2v, w),
                                  __builtin_bit_cast(half2v, h), acc, false);
#else
    half2v wv = __builtin_bit_cast(half2v, w);
    half2v hv = __builtin_bit_cast(half2v, h);
    acc = fmaf((float)wv.x, (float)hv.x, acc);
    return fmaf((float)wv.y, (float)hv.y, acc);
#endif
}
__device__ __forceinline__ float sigm(float x) { return 1.f / (1.f + __expf(-x)); }
__device__ __forceinline__ float tanh_fast(float x) {
    float t = fabsf(x);
    float e = __expf(-2.f * t);
    float r = (1.f - e) / (1.f + e);
    return copysignf(r, x);
}

// ---------------------------------------------------------------------------
// Input-gate GEMM (unchanged from round 3): 64x64 tiles, BK=32, fp32 vector FMA.
// ---------------------------------------------------------------------------
__global__ __launch_bounds__(256, 2) void gates_gemm(
    const int* __restrict__ x, const float* __restrict__ emb,
    const float* __restrict__ Wih, const float* __restrict__ bih,
    const float* __restrict__ bhh, float* __restrict__ Gin, int t0)
{
    __shared__ float As[32][68];
    __shared__ float Bs[32][68];
    __shared__ int xb[64];

    const int tid = threadIdx.x;
    const int bt = blockIdx.x, bk = blockIdx.y;
    if (tid < 64) xb[tid] = x[t0 + bt * 64 + tid];
    __syncthreads();

    const int tx = tid & 15, ty = tid >> 4;
    const int lrow = tid >> 2;
    const int lcol = (tid & 3) * 8;

    const float* arow0 = emb + (size_t)xb[lrow] * 1024 + lcol;
    const float* brow0 = Wih + (size_t)(bk * 64 + lrow) * 1024 + lcol;

    float acc[4][4] = {};

    for (int d0 = 0; d0 < 1024; d0 += 32) {
        float4 a0 = *(const float4*)(arow0 + d0);
        float4 a1 = *(const float4*)(arow0 + d0 + 4);
        float4 b0 = *(const float4*)(brow0 + d0);
        float4 b1 = *(const float4*)(brow0 + d0 + 4);
        __syncthreads();
        As[lcol + 0][lrow] = a0.x; As[lcol + 1][lrow] = a0.y;
        As[lcol + 2][lrow] = a0.z; As[lcol + 3][lrow] = a0.w;
        As[lcol + 4][lrow] = a1.x; As[lcol + 5][lrow] = a1.y;
        As[lcol + 6][lrow] = a1.z; As[lcol + 7][lrow] = a1.w;
        Bs[lcol + 0][lrow] = b0.x; Bs[lcol + 1][lrow] = b0.y;
        Bs[lcol + 2][lrow] = b0.z; Bs[lcol + 3][lrow] = b0.w;
        Bs[lcol + 4][lrow] = b1.x; Bs[lcol + 5][lrow] = b1.y;
        Bs[lcol + 6][lrow] = b1.z; Bs[lcol + 7][lrow] = b1.w;
        __syncthreads();
#pragma unroll
        for (int kk = 0; kk < 32; kk++) {
            float4 av = *(const float4*)&As[kk][ty * 4];
            float4 bv = *(const float4*)&Bs[kk][tx * 4];
#define FMA4(i, aval)                                        \
            acc[i][0] = fmaf(aval, bv.x, acc[i][0]);         \
            acc[i][1] = fmaf(aval, bv.y, acc[i][1]);         \
            acc[i][2] = fmaf(aval, bv.z, acc[i][2]);         \
            acc[i][3] = fmaf(aval, bv.w, acc[i][3]);
            FMA4(0, av.x) FMA4(1, av.y) FMA4(2, av.z) FMA4(3, av.w)
#undef FMA4
        }
    }

    const int kg = bk * 64 + tx * 4;
    float bx = bih[kg + 0] + bhh[kg + 0];
    float by = bih[kg + 1] + bhh[kg + 1];
    float bz = bih[kg + 2] + bhh[kg + 2];
    float bw = bih[kg + 3] + bhh[kg + 3];
#pragma unroll
    for (int i = 0; i < 4; i++) {
        int trow = bt * 64 + ty * 4 + i;
        float4 o;
        o.x = acc[i][0] + bx; o.y = acc[i][1] + by;
        o.z = acc[i][2] + bz; o.w = acc[i][3] + bw;
        *(float4*)&Gin[(size_t)trow * 8192 + kg] = o;
    }
}

// ---------------------------------------------------------------------------
// Persistent sequential LSTM. Block b owns units [b*8, b*8+8) -> 32 gate-rows.
// thread: r = tid>>4 in [0,32) = row (gate*8+unit), s = tid&15 = K-slice of 128.
// Weights: 64 packed-fp16 uints per lane, group-rotated by (j+s)&7 so the
// wave's 16 distinct h-addresses spread across bank groups.
// h is carried as packed fp16 in hbuf (uint[2][1024]) and staged into LDS.
// ---------------------------------------------------------------------------
__global__ __launch_bounds__(NT, 2) void lstm_seq(
    const float* __restrict__ Whh, const float* __restrict__ Gin,
    uint* __restrict__ hbuf /*2 x 1024 packed*/, float* __restrict__ cbuf /*2048*/,
    uint* __restrict__ flags /*NB*/, float* __restrict__ out, int t0, int T)
{
    const int b = blockIdx.x;
    const int tid = threadIdx.x;
    const int r = tid >> 4;       // 0..31
    const int s = tid & 15;       // 0..15
    const int gate = r >> 3;      // 0..3 (i,f,g,o)
    const int ul = r & 7;         // unit local
    const int R = gate * 2048 + b * UPB + ul;   // global row of W_hh

    __shared__ uint hs[1024];     // packed h (2 fp16 per uint)
    __shared__ float sdot[32];
    __shared__ float hloc[UPB];

    // --- load this lane's 128 weights as 64 packed-fp16 uints, group-rotated ---
    uint wreg[64];
    const float* wrow = Whh + (size_t)R * 2048 + s * 128;
#pragma unroll
    for (int j = 0; j < 8; j++) {
        int kg = ((j + s) & 7) * 16;       // 16-half group, rotated
#pragma unroll
        for (int q = 0; q < 4; q++) {
            float4 f = *(const float4*)(wrow + kg + 4 * q);
            wreg[8 * j + 2 * q]     = packh(f.x, f.y);
            wreg[8 * j + 2 * q + 1] = packh(f.z, f.w);
        }
    }
    float c_reg = (tid < UPB) ? cbuf[b * UPB + tid] : 0.f;

    for (int t = 0; t < T; ++t) {
        const int tg = t0 + t;

        // ---- prefetch this step's input-gate contributions (flag-independent) ----
        float gi = 0.f, gf = 0.f, gg = 0.f, go = 0.f;
        if (tid < UPB) {
            const float* gp = Gin + (size_t)t * 8192 + b * UPB + tid;
            gi = gp[0]; gf = gp[2048]; gg = gp[4096]; go = gp[6144];
        }

        // ---- wait for all blocks to have published h_{tg-1} (relaxed, no fences) ----
        if (tid < NB) {
            while (__hip_atomic_load(&flags[tid], __ATOMIC_RELAXED,
                                     __HIP_MEMORY_SCOPE_AGENT) < (uint)tg) {
                __builtin_amdgcn_s_sleep(1);
            }
        }
        asm volatile("" ::: "memory");   // compiler barrier: no hoisting h loads above spin
        __syncthreads();

        // ---- stage packed h into LDS via LLC-coherent loads ----
        const uint* hrd = hbuf + (size_t)(tg & 1) * 1024;
        uint ha = __hip_atomic_load(&hrd[2 * tid],     __ATOMIC_RELAXED, __HIP_MEMORY_SCOPE_AGENT);
        uint hb = __hip_atomic_load(&hrd[2 * tid + 1], __ATOMIC_RELAXED, __HIP_MEMORY_SCOPE_AGENT);
        hs[2 * tid] = ha; hs[2 * tid + 1] = hb;
        __syncthreads();

        // ---- partial dot: 128 halfs = 64 dot2 (fp16 w x fp16 h, fp32 acc) ----
        float acc = 0.f;
        const uint* hbase = &hs[s * 64];
#pragma unroll
        for (int j = 0; j < 8; j++) {
            int kg = ((j + s) & 7) * 8;            // uint group of 8, rotated
            uint4 u0 = *(const uint4*)(hbase + kg);
            uint4 u1 = *(const uint4*)(hbase + kg + 4);
            acc = dot2acc(wreg[8 * j + 0], u0.x, acc);
            acc = dot2acc(wreg[8 * j + 1], u0.y, acc);
            acc = dot2acc(wreg[8 * j + 2], u0.z, acc);
            acc = dot2acc(wreg[8 * j + 3], u0.w, acc);
            acc = dot2acc(wreg[8 * j + 4], u1.x, acc);
            acc = dot2acc(wreg[8 * j + 5], u1.y, acc);
            acc = dot2acc(wreg[8 * j + 6], u1.z, acc);
            acc = dot2acc(wreg[8 * j + 7], u1.w, acc);
        }
        acc += __shfl_xor(acc, 1);
        acc += __shfl_xor(acc, 2);
        acc += __shfl_xor(acc, 4);
        acc += __shfl_xor(acc, 8);
        if (s == 0) sdot[r] = acc;
        __syncthreads();

        // ---- gate math + state update (8 unit-threads, all in wave 0) ----
        if (tid < UPB) {
            float zi = sdot[tid]       + gi;
            float zf = sdot[UPB + tid] + gf;
            float zg = sdot[2 * UPB + tid] + gg;
            float zo = sdot[3 * UPB + tid] + go;
            float si = sigm(zi), sf = sigm(zf), so = sigm(zo);
            float tg_ = tanh_fast(zg);
            c_reg = sf * c_reg + si * tg_;
            float h = so * tanh_fast(c_reg);
            hloc[tid] = h;
            out[(size_t)tg * 2048 + b * UPB + tid] = h;   // fp32 output path
        }
        __syncthreads();

        // ---- publish packed h + flag (all wave 0; vmcnt drain orders them) ----
        if (tid < UPB / 2) {
            uint p = packh(hloc[2 * tid], hloc[2 * tid + 1]);
            __hip_atomic_store(&hbuf[(size_t)((tg + 1) & 1) * 1024 + b * (UPB / 2) + tid],
                               p, __ATOMIC_RELAXED, __HIP_MEMORY_SCOPE_AGENT);
        }
        if (tid == 0) {
            asm volatile("s_waitcnt vmcnt(0)" ::: "memory");  // h stores acked at LLC
            __hip_atomic_store(&flags[b], (uint)(tg + 1), __ATOMIC_RELAXED,
                               __HIP_MEMORY_SCOPE_AGENT);
        }
    }
    if (tid < UPB) cbuf[b * UPB + tid] = c_reg;   // persist c across chunk launches
}

// ---------------------------------------------------------------------------
__global__ void init_state(const float* __restrict__ h0, const float* __restrict__ c0,
                           uint* __restrict__ hbuf, float* __restrict__ cbuf,
                           uint* __restrict__ flags)
{
    int t = blockIdx.x * 256 + threadIdx.x;
    if (t < 1024) hbuf[t] = packh(h0[2 * t], h0[2 * t + 1]);   // buffer 0 = h_{-1}
    if (t < 2048) cbuf[t] = c0[t];
    if (t < NB) flags[t] = 0u;
}

extern "C" void kernel_launch(void* const* d_in, const int* in_sizes, int n_in,
                              void* d_out, int out_size, void* d_ws, size_t ws_size,
                              hipStream_t stream)
{
    const int*   x    = (const int*)d_in[0];
    const float* emb  = (const float*)d_in[1];
    const float* Wih  = (const float*)d_in[2];
    const float* Whh  = (const float*)d_in[3];
    const float* bih  = (const float*)d_in[4];
    const float* bhh  = (const float*)d_in[5];
    const float* h0   = (const float*)d_in[6];
    const float* c0   = (const float*)d_in[7];
    float* out = (float*)d_out;

    // workspace: [flags 1K pad 4K][hbuf 2x4K][cbuf 8K][pad to 32K][Gin T*32K]
    uint*  flags = (uint*)d_ws;
    uint*  hbuf  = (uint*)((char*)d_ws + 4096);
    float* cbuf  = (float*)((char*)d_ws + 4096 + 8192);
    float* Gin   = (float*)((char*)d_ws + 32768);

    int T = 128;
    const int cands[5] = {4096, 2048, 1024, 512, 256};
    for (int i = 0; i < 5; i++) {
        if (32768 + (size_t)cands[i] * 8192 * 4 <= ws_size) { T = cands[i]; break; }
    }

    init_state<<<8, 256, 0, stream>>>(h0, c0, hbuf, cbuf, flags);
    const int nC = 4096 / T;
    for (int c = 0; c < nC; ++c) {
        const int t0 = c * T;
        gates_gemm<<<dim3(T / 64, 128), 256, 0, stream>>>(x, emb, Wih, bih, bhh, Gin, t0);
        lstm_seq<<<NB, NT, 0, stream>>>(Whh, Gin, hbuf, cbuf, flags, out, t0, T);
    }
}